// Round 6
// baseline (162.499 us; speedup 1.0000x reference)
//
#include <hip/hip_runtime.h>

// Problem constants (fixed by the reference)
static constexpr int kB = 2;
static constexpr int kNV = 30000;
static constexpr int kD = 8;    // NDIRS
static constexpr int kR = 3;    // NRINGS
static constexpr int kC = 16;   // C
static constexpr int kF = 16;   // NF
static constexpr int NP = (kB * kNV) / 2;   // 30000 vertex-pairs
static constexpr int S  = 3840;             // pair stride == grid size

static constexpr int NY   = kB * kNV * kD * kC;        // 7,680,000 y elems
static constexpr int NSF  = kB * kNV * kR * kD;        // 1,440,000 gather entries
static constexpr int YCVT_BLOCKS = NY / (256 * 8);     // 3750
static constexpr int OFS_BLOCKS  = NSF / 256;          // 5625

// d_ws layout: [0, 15.36MB) bf16 y copy; [16MB, +5.76MB) gather offsets
static constexpr size_t WS_OFFS = 16u * 1024u * 1024u;

typedef short short8  __attribute__((ext_vector_type(8)));   // 8 bf16
typedef float floatx4 __attribute__((ext_vector_type(4)));   // MFMA acc

static constexpr int PATCH_SZ = 1536;   // 48 entries x 32 B (bf16 row)

__device__ __forceinline__ unsigned bf16rne(float x) {
    unsigned u = __float_as_uint(x);
    return (u + 0x7fffu + ((u >> 16) & 1u)) >> 16;   // round-to-nearest-even
}

// ---------------- Prepass: y -> bf16 copy; sync_field -> element offsets ----
__global__ __launch_bounds__(256) void prep_kernel(
    const float* __restrict__ y, const int* __restrict__ sf,
    unsigned short* __restrict__ yb, int* __restrict__ offs)
{
    const int b = blockIdx.x;
    if (b < YCVT_BLOCKS) {
        const int t = b * 256 + threadIdx.x;           // 0..959999, 8 floats each
        const float4* src = reinterpret_cast<const float4*>(y) + (size_t)t * 2;
        const float4 a = src[0], c = src[1];
        uint4 o;
        o.x = bf16rne(a.x) | (bf16rne(a.y) << 16);
        o.y = bf16rne(a.z) | (bf16rne(a.w) << 16);
        o.z = bf16rne(c.x) | (bf16rne(c.y) << 16);
        o.w = bf16rne(c.z) | (bf16rne(c.w) << 16);
        reinterpret_cast<uint4*>(yb)[t] = o;
    } else {
        const int t = (b - YCVT_BLOCKS) * 256 + threadIdx.x;  // 0..1439999
        const int* s = sf + (size_t)t * 3;
        offs[t] = ((s[0] * kNV + s[1]) * kD + s[2]) * kC;     // elem offset in yb
    }
}

// ---------------- Main: per-pair 16x16 = A[16x416] x B[416x16] via MFMA -----
// K map: k = dd*48 + r*16 + c (conv); k = 384+c (center); 400..415 zero.
__global__ __launch_bounds__(64) void sgc_kernel(
    const unsigned short* __restrict__ yb,   // bf16 y copy
    const int*   __restrict__ offs,          // precomputed gather offsets
    const float* __restrict__ kern,          // (R, D, C, F) fp32
    const float* __restrict__ ck,            // (C, F) fp32
    const float* __restrict__ bias,          // (F,)
    float*       __restrict__ out)           // (B, NV, F)
{
    __shared__ __align__(16) char smem[2 * PATCH_SZ];

    const int lane = threadIdx.x;        // single wave
    const int wid  = blockIdx.x;
    const int f    = lane & 15;          // MFMA col / feature
    const int q    = lane >> 4;          // MFMA k-quad
    const int mvtx = (lane >> 3) & 1;    // A-row vertex-in-pair
    const int md   = lane & 7;           // A-row direction

    // ---- per-lane chunk geometry + B-fragments (once per wave) ----
    int aOfs[12];
    short8 bfrag[13];
#pragma unroll
    for (int kk = 0; kk < 12; ++kk) {
        const int g   = kk * 4 + q;
        const int dd  = (g * 43) >> 8;       // g/6 for g<48
        const int rem = g - dd * 6;
        const int r   = rem >> 1;
        const int ch  = rem & 1;
        const int rot = (md + dd) & 7;
        aOfs[kk] = ((mvtx * 3 + r) * 8 + rot) * 32 + ch * 16;   // bytes
        const int be = ((r * 8 + dd) * 16 + ch * 8) * 16 + f;
        union { unsigned u[4]; short8 v; } t;
#pragma unroll
        for (int j = 0; j < 4; ++j) {
            const float a = kern[be + (2 * j) * 16];
            const float b = kern[be + (2 * j + 1) * 16];
            t.u[j] = bf16rne(a) | (bf16rne(b) << 16);
        }
        bfrag[kk] = t.v;
    }
    {   // center chunk: q=0 -> ck c0-7, q=1 -> c8-15, q>=2 -> zero pad
        union { unsigned u[4]; short8 v; } t;
        if (q < 2) {
#pragma unroll
            for (int j = 0; j < 4; ++j) {
                const float a = ck[(q * 8 + 2 * j) * 16 + f];
                const float b = ck[(q * 8 + 2 * j + 1) * 16 + f];
                t.u[j] = bf16rne(a) | (bf16rne(b) << 16);
            }
        } else {
            t.u[0] = t.u[1] = t.u[2] = t.u[3] = 0u;
        }
        bfrag[12] = t.v;
    }
    const float biasv = bias[f];

    // ---- roles: lanes 0..47 gather patches; center row = lane's own A-row --
    const bool isPatch = lane < 48;              // offs index = 48*p + lane
    const int  cRow    = (lane & 15) * 16;       // center elem offset base

    // ---- prologue: depth-2 data prefetch, depth-3 offset prefetch ----
    const int p0 = wid;
    const int c0 = (p0           < NP) ? p0           : NP - 1;
    const int c1 = (p0 + S       < NP) ? p0 + S       : NP - 1;
    const int c2 = (p0 + 2 * S   < NP) ? p0 + 2 * S   : NP - 1;

    uint4 P[2][2];   // patch rows (32 B bf16)
    uint4 Cc[2][2];  // center rows
    int   off_n = 0;
    {
        int o0 = 0, o1 = 0;
        if (isPatch) {
            o0 = offs[48 * c0 + lane];
            o1 = offs[48 * c1 + lane];
            off_n = offs[48 * c2 + lane];
        }
        if (isPatch) {
            const uint4* gp = reinterpret_cast<const uint4*>(yb + o0);
            P[0][0] = gp[0]; P[0][1] = gp[1];
        }
        {
            const uint4* gp = reinterpret_cast<const uint4*>(yb + 256 * c0 + cRow);
            Cc[0][0] = gp[0]; Cc[0][1] = gp[1];
        }
        if (isPatch) {
            const uint4* gp = reinterpret_cast<const uint4*>(yb + o1);
            P[1][0] = gp[0]; P[1][1] = gp[1];
        }
        {
            const uint4* gp = reinterpret_cast<const uint4*>(yb + 256 * c1 + cRow);
            Cc[1][0] = gp[0]; Cc[1][1] = gp[1];
        }
    }

    int p = p0, cur = 0;
    while (p < NP) {
        // 1. stage patch rows -> LDS buffer `cur`
        if (isPatch) {
            char* wp = smem + cur * PATCH_SZ + lane * 32;
            *(uint4*)(wp)      = P[cur][0];
            *(uint4*)(wp + 16) = P[cur][1];
        }

        // 2. capture center A-frag from this slot's registers (before refill)
        short8 af12;
        {
            union { uint4 u; short8 s; } t0, t1;
            t0.u = Cc[cur][0]; t1.u = Cc[cur][1];
            const short8 z8 = { 0, 0, 0, 0, 0, 0, 0, 0 };
            af12 = (q == 0) ? t0.s : (q == 1) ? t1.s : z8;
        }

        // 3. drain LDS writes (single wave: no barrier, globals stay in flight)
        __asm__ __volatile__("" ::: "memory");
        __builtin_amdgcn_s_waitcnt(0xC07F);   // lgkmcnt(0) only
        __asm__ __volatile__("" ::: "memory");

        // 4. refill slot `cur` with pair p+2S; offset prefetch for p+3S
        {
            const int cn2 = (p + 2 * S < NP) ? p + 2 * S : NP - 1;
            if (isPatch) {
                const uint4* gp = reinterpret_cast<const uint4*>(yb + off_n);
                P[cur][0] = gp[0]; P[cur][1] = gp[1];
            }
            {
                const uint4* gp =
                    reinterpret_cast<const uint4*>(yb + 256 * cn2 + cRow);
                Cc[cur][0] = gp[0]; Cc[cur][1] = gp[1];
            }
            const int cn3 = (p + 3 * S < NP) ? p + 3 * S : NP - 1;
            if (isPatch) off_n = offs[48 * cn3 + lane];
        }

        // 5. 13x MFMA, two accumulator chains
        floatx4 acc0 = { biasv, biasv, biasv, biasv };
        floatx4 acc1 = { 0.f, 0.f, 0.f, 0.f };
        const char* pb = smem + cur * PATCH_SZ;
#pragma unroll
        for (int kk = 0; kk < 12; kk += 2) {
            const short8 a0 = *(const short8*)(pb + aOfs[kk]);
            const short8 a1 = *(const short8*)(pb + aOfs[kk + 1]);
            acc0 = __builtin_amdgcn_mfma_f32_16x16x32_bf16(a0, bfrag[kk], acc0, 0, 0, 0);
            acc1 = __builtin_amdgcn_mfma_f32_16x16x32_bf16(a1, bfrag[kk + 1], acc1, 0, 0, 0);
        }
        acc0 = __builtin_amdgcn_mfma_f32_16x16x32_bf16(af12, bfrag[12], acc0, 0, 0, 0);

        // 6. epilogue: combine, relu, max over rows, store
        float mx = fmaxf(fmaxf(acc0[0] + acc1[0], acc0[1] + acc1[1]),
                         fmaxf(acc0[2] + acc1[2], acc0[3] + acc1[3]));
        mx = fmaxf(mx, 0.0f);
        mx = fmaxf(mx, __shfl_xor(mx, 16, 64));
        if (((lane >> 4) & 1) == 0)
            out[(2 * p + (lane >> 5)) * kF + f] = mx;

        p += S;
        cur ^= 1;
    }
}

extern "C" void kernel_launch(void* const* d_in, const int* in_sizes, int n_in,
                              void* d_out, int out_size, void* d_ws, size_t ws_size,
                              hipStream_t stream) {
    const float* y    = reinterpret_cast<const float*>(d_in[0]);
    const int*   sf   = reinterpret_cast<const int*>(d_in[1]);
    const float* kern = reinterpret_cast<const float*>(d_in[2]);
    const float* ck   = reinterpret_cast<const float*>(d_in[3]);
    const float* bias = reinterpret_cast<const float*>(d_in[4]);
    float* out = reinterpret_cast<float*>(d_out);

    unsigned short* yb = reinterpret_cast<unsigned short*>(d_ws);
    int* offs = reinterpret_cast<int*>((char*)d_ws + WS_OFFS);

    prep_kernel<<<YCVT_BLOCKS + OFS_BLOCKS, 256, 0, stream>>>(y, sf, yb, offs);
    sgc_kernel<<<S, 64, 0, stream>>>(yb, offs, kern, ck, bias, out);
}

// Round 7
// 141.282 us; speedup vs baseline: 1.1502x; 1.1502x over previous
//
#include <hip/hip_runtime.h>

// Problem constants (fixed by the reference)
static constexpr int kB = 2;
static constexpr int kNV = 30000;
static constexpr int kD = 8;    // NDIRS
static constexpr int kR = 3;    // NRINGS
static constexpr int kC = 16;   // C
static constexpr int kF = 16;   // NF
static constexpr int NP = (kB * kNV) / 2;   // 30000 vertex-pairs
static constexpr int NW = 7500;             // total waves; 4 pairs per wave
static constexpr int S  = NW;               // pair stride
static constexpr int WPB = 4;               // waves per block (independent)

typedef short short8  __attribute__((ext_vector_type(8)));   // 8 bf16
typedef float floatx4 __attribute__((ext_vector_type(4)));   // MFMA acc

static constexpr int PATCH_SZ = 1536;   // 48 entries x 32 B bf16 row

__device__ __forceinline__ unsigned bf16rne(float x) {
    unsigned u = __float_as_uint(x);
    return (u + 0x7fffu + ((u >> 16) & 1u)) >> 16;   // round-to-nearest-even
}

// Per-pair GEMM: D[16x16] = A[16x416] x B[416x16].
// K map: k = dd*48 + r*16 + c (conv, k<384); k = 384+c (center); 400..415 zero.
// A-row m = vertex_in_pair*8 + dir.  B col = feature f.
__global__ __launch_bounds__(256) void sgc_kernel(
    const float* __restrict__ y,          // (B, NV, NDIRS, C) fp32
    const int*   __restrict__ sync_field, // (B, NV, NRINGS, NDIRS, 3)
    const float* __restrict__ kern,       // (R, D, C, F) fp32
    const float* __restrict__ ck,         // (C, F) fp32
    const float* __restrict__ bias,       // (F,)
    float*       __restrict__ out)        // (B, NV, F)
{
    // 4 independent waves, private double-buffered patch LDS (no barriers).
    __shared__ __align__(16) char smem[WPB * 2 * PATCH_SZ];

    const int lane   = threadIdx.x & 63;
    const int wlocal = threadIdx.x >> 6;
    const int wg     = blockIdx.x * WPB + wlocal;   // 0..7499
    char* wbase = smem + wlocal * (2 * PATCH_SZ);

    const int f    = lane & 15;          // MFMA col / feature
    const int q    = lane >> 4;          // MFMA k-quad
    const int mvtx = (lane >> 3) & 1;    // A-row vertex-in-pair
    const int md   = lane & 7;           // A-row direction

    // ---- per-lane chunk geometry + B-fragments (once per wave) ----
    int aOfs[12];
    short8 bfrag[13];
#pragma unroll
    for (int kk = 0; kk < 12; ++kk) {
        const int g   = kk * 4 + q;
        const int dd  = (g * 43) >> 8;       // g/6 for g<48
        const int rem = g - dd * 6;
        const int r   = rem >> 1;
        const int ch  = rem & 1;
        const int rot = (md + dd) & 7;
        aOfs[kk] = ((mvtx * 3 + r) * 8 + rot) * 32 + ch * 16;   // bytes
        const int be = ((r * 8 + dd) * 16 + ch * 8) * 16 + f;
        union { unsigned u[4]; short8 v; } t;
#pragma unroll
        for (int j = 0; j < 4; ++j) {
            const float a = kern[be + (2 * j) * 16];
            const float b = kern[be + (2 * j + 1) * 16];
            t.u[j] = bf16rne(a) | (bf16rne(b) << 16);
        }
        bfrag[kk] = t.v;
    }
    {   // center B-chunk: q=0 -> ck c0-7, q=1 -> c8-15, q>=2 -> zeros
        union { unsigned u[4]; short8 v; } t;
        if (q < 2) {
#pragma unroll
            for (int j = 0; j < 4; ++j) {
                const float a = ck[(q * 8 + 2 * j) * 16 + f];
                const float b = ck[(q * 8 + 2 * j + 1) * 16 + f];
                t.u[j] = bf16rne(a) | (bf16rne(b) << 16);
            }
        } else {
            t.u[0] = t.u[1] = t.u[2] = t.u[3] = 0u;
        }
        bfrag[12] = t.v;
    }
    const float biasv = bias[f];

    // ---- roles ----
    const bool isPatch = lane < 48;          // patch entry = lane (vtx,r,dir)
    const int  cenElem = (lane & 15) * 16;   // center A-row m=(lane&15): 16*m

    // ---- prologue: gather pair p0; sf for p0+S ----
    int p = wg;
    float4 g0, g1, g2, g3;     // patch row (64 B fp32)
    float4 c0, c1, c2, c3;     // center row (64 B fp32)
    int sB0 = 0, sB1 = 0, sB2 = 0;
    {
        if (isPatch) {
            const int* s = sync_field + (size_t)(p * 48 + lane) * 3;
            const int a0 = s[0], a1 = s[1], a2 = s[2];
            const float4* gp = reinterpret_cast<const float4*>(
                y + ((a0 * kNV + a1) * kD + a2) * kC);
            g0 = gp[0]; g1 = gp[1]; g2 = gp[2]; g3 = gp[3];
        }
        const float4* cp = reinterpret_cast<const float4*>(y + p * 256 + cenElem);
        c0 = cp[0]; c1 = cp[1]; c2 = cp[2]; c3 = cp[3];
        if (isPatch) {
            const int* s = sync_field + (size_t)((p + S) * 48 + lane) * 3;
            sB0 = s[0]; sB1 = s[1]; sB2 = s[2];
        }
    }

#pragma unroll
    for (int it = 0; it < 4; ++it) {
        char* pb = wbase + (it & 1) * PATCH_SZ;

        // 1. convert + stage patch row -> LDS
        if (isPatch) {
            unsigned wu[8];
            const float4 gg[4] = { g0, g1, g2, g3 };
#pragma unroll
            for (int i = 0; i < 4; ++i) {
                wu[2 * i]     = bf16rne(gg[i].x) | (bf16rne(gg[i].y) << 16);
                wu[2 * i + 1] = bf16rne(gg[i].z) | (bf16rne(gg[i].w) << 16);
            }
            char* wp = pb + lane * 32;
            *(uint4*)(wp)      = make_uint4(wu[0], wu[1], wu[2], wu[3]);
            *(uint4*)(wp + 16) = make_uint4(wu[4], wu[5], wu[6], wu[7]);
        }

        // 2. center A-frag from registers (before prefetch overwrites)
        short8 af12;
        {
            const float4 cc[4] = { c0, c1, c2, c3 };
            const int h = (q < 2) ? q * 2 : 0;
            union { unsigned u[4]; short8 v; } t;
            t.u[0] = bf16rne(cc[h].x) | (bf16rne(cc[h].y) << 16);
            t.u[1] = bf16rne(cc[h].z) | (bf16rne(cc[h].w) << 16);
            t.u[2] = bf16rne(cc[h + 1].x) | (bf16rne(cc[h + 1].y) << 16);
            t.u[3] = bf16rne(cc[h + 1].z) | (bf16rne(cc[h + 1].w) << 16);
            const short8 z8 = { 0, 0, 0, 0, 0, 0, 0, 0 };
            af12 = (q < 2) ? t.v : z8;
        }

        // 3. prefetch pair p+S; sf for p+2S
        if (it < 3) {
            if (isPatch) {
                const float4* gp = reinterpret_cast<const float4*>(
                    y + ((sB0 * kNV + sB1) * kD + sB2) * kC);
                g0 = gp[0]; g1 = gp[1]; g2 = gp[2]; g3 = gp[3];
            }
            const float4* cp =
                reinterpret_cast<const float4*>(y + (p + S) * 256 + cenElem);
            c0 = cp[0]; c1 = cp[1]; c2 = cp[2]; c3 = cp[3];
            if (it < 2 && isPatch) {
                const int* s =
                    sync_field + (size_t)((p + 2 * S) * 48 + lane) * 3;
                sB0 = s[0]; sB1 = s[1]; sB2 = s[2];
            }
        }

        // 4. drain LDS writes only (vmcnt stays outstanding; no barrier —
        //    each wave owns its LDS slice)
        __asm__ __volatile__("" ::: "memory");
        __builtin_amdgcn_s_waitcnt(0xC07F);   // lgkmcnt(0) only
        __asm__ __volatile__("" ::: "memory");

        // 5. 13x MFMA, two accumulator chains
        floatx4 acc0 = { biasv, biasv, biasv, biasv };
        floatx4 acc1 = { 0.f, 0.f, 0.f, 0.f };
#pragma unroll
        for (int kk = 0; kk < 12; kk += 2) {
            const short8 a0 = *(const short8*)(pb + aOfs[kk]);
            const short8 a1 = *(const short8*)(pb + aOfs[kk + 1]);
            acc0 = __builtin_amdgcn_mfma_f32_16x16x32_bf16(a0, bfrag[kk], acc0, 0, 0, 0);
            acc1 = __builtin_amdgcn_mfma_f32_16x16x32_bf16(a1, bfrag[kk + 1], acc1, 0, 0, 0);
        }
        acc0 = __builtin_amdgcn_mfma_f32_16x16x32_bf16(af12, bfrag[12], acc0, 0, 0, 0);

        // 6. epilogue: combine, relu, max over rows, store
        float mx = fmaxf(fmaxf(acc0[0] + acc1[0], acc0[1] + acc1[1]),
                         fmaxf(acc0[2] + acc1[2], acc0[3] + acc1[3]));
        mx = fmaxf(mx, 0.0f);
        mx = fmaxf(mx, __shfl_xor(mx, 16, 64));   // rows 0-7 / 8-15 per vertex
        if (((lane >> 4) & 1) == 0)
            out[(2 * p + (lane >> 5)) * kF + f] = mx;

        p += S;
    }
}

extern "C" void kernel_launch(void* const* d_in, const int* in_sizes, int n_in,
                              void* d_out, int out_size, void* d_ws, size_t ws_size,
                              hipStream_t stream) {
    const float* y    = reinterpret_cast<const float*>(d_in[0]);
    const int*   sf   = reinterpret_cast<const int*>(d_in[1]);
    const float* kern = reinterpret_cast<const float*>(d_in[2]);
    const float* ck   = reinterpret_cast<const float*>(d_in[3]);
    const float* bias = reinterpret_cast<const float*>(d_in[4]);
    float* out = reinterpret_cast<float*>(d_out);

    sgc_kernel<<<NW / WPB, WPB * 64, 0, stream>>>(y, sf, kern, ck, bias, out);
}

// Round 8
// 117.169 us; speedup vs baseline: 1.3869x; 1.2058x over previous
//
#include <hip/hip_runtime.h>

// Problem constants (fixed by the reference)
static constexpr int kB = 2;
static constexpr int kNV = 30000;
static constexpr int kD = 8;    // NDIRS
static constexpr int kR = 3;    // NRINGS
static constexpr int kC = 16;   // C
static constexpr int kF = 16;   // NF
static constexpr int NP = (kB * kNV) / 2;   // 30000 vertex-pairs
static constexpr int S  = 3840;             // pair stride == #waves (single-wave blocks)

typedef short short8  __attribute__((ext_vector_type(8)));   // 8 bf16
typedef float floatx4 __attribute__((ext_vector_type(4)));   // MFMA acc

// Per-wave LDS: two buffers of [patch 48x32B | center 16x64B(32 data + 32 zeros)]
static constexpr int CENT_OFS   = 1536;
static constexpr int BUF_STRIDE = 2560;

__device__ __forceinline__ unsigned bf16rne(float x) {
    unsigned u = __float_as_uint(x);
    return (u + 0x7fffu + ((u >> 16) & 1u)) >> 16;   // round-to-nearest-even
}

// Per-pair GEMM: D[16x16] = A[16x416] x B[416x16].
// K map: k = dd*48 + r*16 + c (conv, k<384); k = 384+c (center); 400..415 zero.
__global__ __launch_bounds__(64) void sgc_kernel(
    const float* __restrict__ y,          // (B, NV, NDIRS, C) fp32
    const int*   __restrict__ sync_field, // (B, NV, NRINGS, NDIRS, 3)
    const float* __restrict__ kern,       // (R, D, C, F) fp32
    const float* __restrict__ ck,         // (C, F) fp32
    const float* __restrict__ bias,       // (F,)
    float*       __restrict__ out)        // (B, NV, F)
{
    __shared__ __align__(16) char smem[2 * BUF_STRIDE];

    const int lane = threadIdx.x;        // single wave per block
    const int wid  = blockIdx.x;
    const int f    = lane & 15;          // MFMA col / feature
    const int q    = lane >> 4;          // MFMA k-quad
    const int mvtx = (lane >> 3) & 1;    // A-row vertex-in-pair
    const int md   = lane & 7;           // A-row direction

    // ---- one-time: zero the 32B upper half of all 16 center slots, both bufs
    {
        const int buf = lane >> 5, z = lane & 31;
        const int ofs = buf * BUF_STRIDE + CENT_OFS + (z >> 1) * 64 + 32 + (z & 1) * 16;
        *(uint4*)(smem + ofs) = make_uint4(0u, 0u, 0u, 0u);
    }

    // ---- per-lane chunk geometry + B-fragments (once per wave) ----
    int aOfs[12];
    short8 bfrag[13];
#pragma unroll
    for (int kk = 0; kk < 12; ++kk) {
        const int g   = kk * 4 + q;
        const int dd  = (g * 43) >> 8;       // g/6 for g<48
        const int rem = g - dd * 6;
        const int r   = rem >> 1;
        const int ch  = rem & 1;
        const int rot = (md + dd) & 7;
        aOfs[kk] = ((mvtx * 3 + r) * 8 + rot) * 32 + ch * 16;   // bytes
        const int be = ((r * 8 + dd) * 16 + ch * 8) * 16 + f;
        union { unsigned u[4]; short8 v; } t;
#pragma unroll
        for (int j = 0; j < 4; ++j) {
            const float a = kern[be + (2 * j) * 16];
            const float b = kern[be + (2 * j + 1) * 16];
            t.u[j] = bf16rne(a) | (bf16rne(b) << 16);
        }
        bfrag[kk] = t.v;
    }
    {   // center B-chunk: q=0 -> ck c0-7, q=1 -> c8-15, q>=2 -> zeros
        union { unsigned u[4]; short8 v; } t;
        if (q < 2) {
#pragma unroll
            for (int j = 0; j < 4; ++j) {
                const float a = ck[(q * 8 + 2 * j) * 16 + f];
                const float b = ck[(q * 8 + 2 * j + 1) * 16 + f];
                t.u[j] = bf16rne(a) | (bf16rne(b) << 16);
            }
        } else {
            t.u[0] = t.u[1] = t.u[2] = t.u[3] = 0u;
        }
        bfrag[12] = t.v;
    }
    const float biasv = bias[f];

    // ---- roles: lanes 0..47 gather patch entry `lane`; 48..63 center row m --
    const bool isPatch = lane < 48;
    const int  cenElem = (lane & 15) * 16;   // center row m -> elem offset in pair

    auto cl = [](int v) { return v < NP ? v : NP - 1; };

    int t0 = 0, t1 = 0, t2 = 0;   // sf triple for the NEXT patch issue
    float4 A0, A1, A2, A3, B0, B1, B2, B3;

#define SF_PRE(cc) do { if (isPatch) { \
        const int* s_ = sync_field + (size_t)((cc) * 48 + lane) * 3; \
        t0 = s_[0]; t1 = s_[1]; t2 = s_[2]; } } while (0)

#define ISSUE_G(Rv, cc) do { \
        const float4* gp_; \
        if (isPatch) \
            gp_ = reinterpret_cast<const float4*>( \
                y + ((t0 * kNV + t1) * kD + t2) * kC); \
        else \
            gp_ = reinterpret_cast<const float4*>( \
                y + (size_t)(cc) * 256 + cenElem); \
        Rv##0 = gp_[0]; Rv##1 = gp_[1]; Rv##2 = gp_[2]; Rv##3 = gp_[3]; \
    } while (0)

#define STAGE(Rv, bufbase) do { \
        unsigned wu_[8]; \
        const float4 gg_[4] = { Rv##0, Rv##1, Rv##2, Rv##3 }; \
        _Pragma("unroll") \
        for (int i_ = 0; i_ < 4; ++i_) { \
            wu_[2 * i_]     = bf16rne(gg_[i_].x) | (bf16rne(gg_[i_].y) << 16); \
            wu_[2 * i_ + 1] = bf16rne(gg_[i_].z) | (bf16rne(gg_[i_].w) << 16); \
        } \
        char* wp_ = (bufbase) + (isPatch ? lane * 32 : CENT_OFS + cenElem * 4); \
        *(uint4*)(wp_)      = make_uint4(wu_[0], wu_[1], wu_[2], wu_[3]); \
        *(uint4*)(wp_ + 16) = make_uint4(wu_[4], wu_[5], wu_[6], wu_[7]); \
    } while (0)

#define DRAIN do { \
        __asm__ __volatile__("" ::: "memory"); \
        __builtin_amdgcn_s_waitcnt(0xC07F); /* lgkmcnt(0) only */ \
        __asm__ __volatile__("" ::: "memory"); \
    } while (0)

#define COMPUTE_STORE(bufbase, pp) do { \
        floatx4 acc0 = { biasv, biasv, biasv, biasv }; \
        floatx4 acc1 = { 0.f, 0.f, 0.f, 0.f }; \
        _Pragma("unroll") \
        for (int kk_ = 0; kk_ < 12; kk_ += 2) { \
            const short8 a0_ = *(const short8*)((bufbase) + aOfs[kk_]); \
            const short8 a1_ = *(const short8*)((bufbase) + aOfs[kk_ + 1]); \
            acc0 = __builtin_amdgcn_mfma_f32_16x16x32_bf16(a0_, bfrag[kk_], acc0, 0, 0, 0); \
            acc1 = __builtin_amdgcn_mfma_f32_16x16x32_bf16(a1_, bfrag[kk_ + 1], acc1, 0, 0, 0); \
        } \
        { \
            const short8 ac_ = *(const short8*)((bufbase) + CENT_OFS \
                                                + (lane & 15) * 64 + q * 16); \
            acc0 = __builtin_amdgcn_mfma_f32_16x16x32_bf16(ac_, bfrag[12], acc0, 0, 0, 0); \
        } \
        float mx = fmaxf(fmaxf(acc0[0] + acc1[0], acc0[1] + acc1[1]), \
                         fmaxf(acc0[2] + acc1[2], acc0[3] + acc1[3])); \
        mx = fmaxf(mx, 0.0f); \
        mx = fmaxf(mx, __shfl_xor(mx, 16, 64)); \
        if (((lane >> 4) & 1) == 0) \
            out[(2 * (pp) + (lane >> 5)) * kF + f] = mx; \
    } while (0)

    // ---- prologue: LDS0 <- p; B in flight (p+S); A in flight (p+2S);
    //      t = sf(p+3S). Steady-state MLP = 2 gather batches / lane.
    int p = wid;                       // wid < 3840 <= NP
    SF_PRE(p);
    ISSUE_G(A, p);
    SF_PRE(cl(p + S));
    ISSUE_G(B, cl(p + S));
    SF_PRE(cl(p + 2 * S));
    STAGE(A, smem);                    // waits A only; B stays in flight
    ISSUE_G(A, cl(p + 2 * S));
    SF_PRE(cl(p + 3 * S));

    for (;;) {
        // even step: compute buf0 (pair p); stage B (p+S) -> buf1
        STAGE(B, smem + BUF_STRIDE);   // waits B; A stays in flight
        ISSUE_G(B, cl(p + 3 * S));
        SF_PRE(cl(p + 4 * S));
        DRAIN;
        COMPUTE_STORE(smem, p);
        p += S; if (p >= NP) break;

        // odd step: compute buf1 (pair p); stage A (p+S) -> buf0
        STAGE(A, smem);                // waits A; B stays in flight
        ISSUE_G(A, cl(p + 3 * S));
        SF_PRE(cl(p + 4 * S));
        DRAIN;
        COMPUTE_STORE(smem + BUF_STRIDE, p);
        p += S; if (p >= NP) break;
    }

#undef SF_PRE
#undef ISSUE_G
#undef STAGE
#undef DRAIN
#undef COMPUTE_STORE
}

extern "C" void kernel_launch(void* const* d_in, const int* in_sizes, int n_in,
                              void* d_out, int out_size, void* d_ws, size_t ws_size,
                              hipStream_t stream) {
    const float* y    = reinterpret_cast<const float*>(d_in[0]);
    const int*   sf   = reinterpret_cast<const int*>(d_in[1]);
    const float* kern = reinterpret_cast<const float*>(d_in[2]);
    const float* ck   = reinterpret_cast<const float*>(d_in[3]);
    const float* bias = reinterpret_cast<const float*>(d_in[4]);
    float* out = reinterpret_cast<float*>(d_out);

    sgc_kernel<<<S, 64, 0, stream>>>(y, sf, kern, ck, bias, out);
}